// Round 12
// baseline (340.066 us; speedup 1.0000x reference)
//
#include <hip/hip_runtime.h>
#include <math.h>

// L=1024 B=2 F=1024 E=2 H=2048 N=16 R=64 K=4, M=2048 rows (m = l*2+b).
// Round-12:
//   - scan: exp2f (libm, denormal-guarded — the r11 regression) replaced by
//     __builtin_amdgcn_exp2f (bare v_exp_f32). Keeps ln2 folded into A.
//   - conv: gls_k templated on MROWS; conv uses 64x64 tiles -> 1024 blocks
//     (4 blocks/CU instead of 2) to fix its latency-bound starvation.
// Everything else identical to round 11.

typedef unsigned short u16;
typedef unsigned int u32;
typedef __attribute__((ext_vector_type(8))) short short8;
typedef __attribute__((ext_vector_type(4))) float floatx4;
typedef __attribute__((ext_vector_type(4))) u16 ushort4v;

__device__ __forceinline__ u16 f2bf(float f) {
    u32 u = __float_as_uint(f);
    return (u16)((u + 0x7fffu + ((u >> 16) & 1u)) >> 16);
}
__device__ __forceinline__ float bf2f(u16 v) {
    return __uint_as_float((u32)v << 16);
}
__device__ __forceinline__ float fexp2(float x) {
    return __builtin_amdgcn_exp2f(x);   // bare v_exp_f32
}

// 16-lane sum reduction on the VALU pipe (DPP), no DS ops.
__device__ __forceinline__ float dpp_red16(float v) {
    v += __uint_as_float((u32)__builtin_amdgcn_update_dpp(
        0, (int)__float_as_uint(v), 0xB1, 0xF, 0xF, true));
    v += __uint_as_float((u32)__builtin_amdgcn_update_dpp(
        0, (int)__float_as_uint(v), 0x4E, 0xF, 0xF, true));
    v += __uint_as_float((u32)__builtin_amdgcn_update_dpp(
        0, (int)__float_as_uint(v), 0x141, 0xF, 0xF, true));
    v += __uint_as_float((u32)__builtin_amdgcn_update_dpp(
        0, (int)__float_as_uint(v), 0x128, 0xF, 0xF, true));
    return v;
}

// async global->LDS, 16 bytes per lane
__device__ __forceinline__ void gl_lds16(const u16* g, u16* l) {
    auto gp = reinterpret_cast<const __attribute__((address_space(1))) u32*>(
        reinterpret_cast<uintptr_t>(g));
    auto lp = reinterpret_cast<__attribute__((address_space(3))) u32*>(
        reinterpret_cast<uintptr_t>(l));
    __builtin_amdgcn_global_load_lds(gp, lp, 16, 0, 0);
}

// ---------------- device transpose body (fp32 -> bf16, S[R][C] -> D[C][R]) --------
__device__ __forceinline__ void trans_dev(const float* __restrict__ S,
                                          u16* __restrict__ D, int R, int C,
                                          int bx, int by)
{
    __shared__ u16 t[64][65];
    int br = bx * 64;
    int bc = by * 64;
    int c = threadIdx.x & 63;
    int r0 = threadIdx.x >> 6;
#pragma unroll
    for (int i = 0; i < 16; ++i) {
        int r = r0 + i * 4;
        float v = 0.f;
        if (br + r < R && bc + c < C) v = S[(size_t)(br + r) * C + bc + c];
        t[r][c] = f2bf(v);
    }
    __syncthreads();
    int cc0 = threadIdx.x >> 4;
    int rr0 = (threadIdx.x & 15) * 4;
#pragma unroll
    for (int i = 0; i < 4; ++i) {
        int cc = i * 16 + cc0;
        if (bc + cc < C) {
            ushort4v o;
#pragma unroll
            for (int k = 0; k < 4; ++k) o[k] = t[rr0 + k][cc];
            *(ushort4v*)(D + (size_t)(bc + cc) * R + br + rr0) = o;
        }
    }
}

// ---------------- prep: all transposes + x convert, one launch ----------------
__global__ __launch_bounds__(256) void prep_k(
    const float* __restrict__ Wc, u16* __restrict__ WTc,
    const float* __restrict__ Wi, u16* __restrict__ WTi,
    const float* __restrict__ Wo, u16* __restrict__ WTo,
    const float* __restrict__ Ws, u16* __restrict__ WTs,
    const float* __restrict__ Wd, u16* __restrict__ WTd,
    const float* __restrict__ x,  u16* __restrict__ xb)
{
    int b = blockIdx.x;
    if (b < 2048) { trans_dev(Wc, WTc, 4096, 2048, b & 63, b >> 6); return; }
    b -= 2048;
    if (b < 1024) { trans_dev(Wi, WTi, 1024, 4096, b & 15, b >> 4); return; }
    b -= 1024;
    if (b < 512)  { trans_dev(Wo, WTo, 2048, 1024, b & 31, b >> 5); return; }
    b -= 512;
    if (b < 64)   { trans_dev(Ws, WTs, 2048, 96,   b & 31, b >> 5); return; }
    b -= 64;
    if (b < 32)   { trans_dev(Wd, WTd, 64, 2048,   0,      b);      return; }
    b -= 32;
    {   // x fp32 -> bf16, 2048 blocks
        int i = (b * 256 + threadIdx.x) * 4;
        float4 v = *(const float4*)(x + i);
        u16 o[4] = {f2bf(v.x), f2bf(v.y), f2bf(v.z), f2bf(v.w)};
        *(ulong1*)(xb + i) = *(ulong1*)o;
    }
}

// ---------------- bf16 [2048][2048] transpose (zT -> z_mh) ----------------
__global__ __launch_bounds__(256) void tbf_k(const u16* __restrict__ S,
                                             u16* __restrict__ D)
{
    __shared__ u16 t[64][68];
    int br = blockIdx.x * 64;
    int bc = blockIdx.y * 64;
    int c = threadIdx.x & 63;
    int r0 = threadIdx.x >> 6;
#pragma unroll
    for (int i = 0; i < 16; ++i) {
        int r = r0 + i * 4;
        t[r][c] = S[(size_t)(br + r) * 2048 + bc + c];
    }
    __syncthreads();
#pragma unroll
    for (int i = 0; i < 16; ++i) {
        int r = r0 + i * 4;
        D[(size_t)(bc + r) * 2048 + br + c] = t[c][r];
    }
}

// ------- proj converts: blocks 0..127 -> dt cols 64..127 to pb_dt bf16 [2048][64]
//         blocks 128..191 -> BC cols 0..31 to bc16 bf16 [2048][32]
__global__ __launch_bounds__(256) void cvtp_k(const float* __restrict__ proj,
                                              u16* __restrict__ pb,
                                              u16* __restrict__ bc)
{
    if (blockIdx.x < 128) {
        int g = blockIdx.x * 256 + threadIdx.x;
        int m = g >> 4, i = (g & 15) * 4;
        float4 v = *(const float4*)(proj + (size_t)m * 128 + 64 + i);
        u16 o[4] = {f2bf(v.x), f2bf(v.y), f2bf(v.z), f2bf(v.w)};
        *(ulong1*)(pb + (size_t)m * 64 + i) = *(ulong1*)o;
    } else {
        int g = (blockIdx.x - 128) * 256 + threadIdx.x;
        int m = g >> 3, i = (g & 7) * 4;
        float4 v = *(const float4*)(proj + (size_t)m * 128 + i);
        u16 o[4] = {f2bf(v.x), f2bf(v.y), f2bf(v.z), f2bf(v.w)};
        *(ulong1*)(bc + (size_t)m * 32 + i) = *(ulong1*)o;
    }
}

// ================= m97-style GEMM: A[M][K] x B[N][K]^T, tile MROWSx64, BK=64 =======
// MODE 0: G1 split — bn<2048: xs[m][h] via LDS repack; else resT[h][m] direct
// MODE 1: conv gather (+zero-fix), +bias+silu -> u_mh (repack) + uT direct
// MODE 3: split-K (gridDim.z), fp32 atomicAdd into zeroed Cf
template<int MODE, int MROWS>
__global__ __launch_bounds__(256) void gls_k(
    const u16* __restrict__ A, int lda,
    const u16* __restrict__ B, int ldb,
    float* __restrict__ Cf, int ldc,
    u16* __restrict__ Cb0, u16* __restrict__ Cb1,
    const float* __restrict__ bias, int nkt)
{
    __shared__ u16 As[MROWS * 64];
    __shared__ u16 Bs[64 * 64];
    const int TI = MROWS / 64;           // 2 (128-tile) or 1 (64-tile)
    const int tid = threadIdx.x;
    const int bm = blockIdx.y * MROWS;
    const int bn = blockIdx.x * 64;
    const int kofs = (MODE == 3) ? blockIdx.z * nkt * 64 : 0;
    const int gofs = (MODE == 1 && bn >= 1024) ? 1024 : 0;
    const int lane = tid & 63, wave = tid >> 6, wm = wave * (MROWS / 4);
    const int m16 = lane & 15, q = lane >> 4;
    floatx4 acc[TI][4] = {};

    const int rsub = lane >> 3;
    const int pch  = lane & 7;

    for (int kt = 0; kt < nkt; ++kt) {
        const int k0 = kofs + kt * 64;
        int tap = 0, ck = k0;
        if (MODE == 1) { tap = k0 >> 10; ck = k0 & 1023; }
#pragma unroll
        for (int i = 0; i < MROWS / 32; ++i) {
            int r = i * 32 + wave * 8 + rsub;
            int c = pch ^ (r & 7);
            const u16* g;
            if (MODE == 1) {
                int rg = bm + r + 2 * tap - 6;
                g = A + (size_t)rg * lda + gofs + ck + c * 8;
            } else {
                g = A + (size_t)(bm + r) * lda + k0 + c * 8;
            }
            gl_lds16(g, As + i * 2048 + wave * 512);
        }
#pragma unroll
        for (int i = 0; i < 2; ++i) {
            int r = i * 32 + wave * 8 + rsub;
            int c = pch ^ (r & 7);
            gl_lds16(B + (size_t)(bn + r) * ldb + k0 + c * 8,
                     Bs + i * 2048 + wave * 512);
        }
        if (MODE == 1 && bm == 0) {
            int zr = 6 - 2 * tap;
            if (zr > 0) {
                asm volatile("s_waitcnt vmcnt(0)" ::: "memory");
                if (tid < 64) {
                    int r = tid >> 3;
                    if (r < zr) *(short8*)(As + r * 64 + (tid & 7) * 8) = short8{};
                }
            }
        }
        __syncthreads();

#pragma unroll
        for (int ks = 0; ks < 2; ++ks) {
            short8 af[TI], bfr[4];
#pragma unroll
            for (int ti = 0; ti < TI; ++ti) {
                int r = wm + ti * 16 + m16;
                int p = (ks * 4 + q) ^ (r & 7);
                af[ti] = *(const short8*)(As + r * 64 + p * 8);
            }
#pragma unroll
            for (int tj = 0; tj < 4; ++tj) {
                int r = tj * 16 + m16;
                int p = (ks * 4 + q) ^ (r & 7);
                bfr[tj] = *(const short8*)(Bs + r * 64 + p * 8);
            }
#pragma unroll
            for (int ti = 0; ti < TI; ++ti)
#pragma unroll
                for (int tj = 0; tj < 4; ++tj)
                    acc[ti][tj] = __builtin_amdgcn_mfma_f32_16x16x32_bf16(
                        af[ti], bfr[tj], acc[ti][tj], 0, 0, 0);
        }
        __syncthreads();
    }

    if (MODE == 3) {
#pragma unroll
        for (int tj = 0; tj < 4; ++tj) {
            int gn = bn + tj * 16 + m16;
#pragma unroll
            for (int ti = 0; ti < TI; ++ti) {
                int gm0 = bm + wm + ti * 16 + q * 4;
#pragma unroll
                for (int r = 0; r < 4; ++r)
                    atomicAdd(Cf + (size_t)(gm0 + r) * ldc + gn, acc[ti][tj][r]);
            }
        }
        return;
    }
    if (MODE == 0 && bn >= 2048) {
#pragma unroll
        for (int tj = 0; tj < 4; ++tj) {
            int gn = bn + tj * 16 + m16;
#pragma unroll
            for (int ti = 0; ti < TI; ++ti) {
                int gm0 = bm + wm + ti * 16 + q * 4;
                ushort4v h;
#pragma unroll
                for (int r = 0; r < 4; ++r) h[r] = f2bf(acc[ti][tj][r]);
                *(ushort4v*)(Cb1 + (size_t)(gn - 2048) * 2048 + gm0) = h;
            }
        }
        return;
    }
#pragma unroll
    for (int tj = 0; tj < 4; ++tj) {
        int gn = bn + tj * 16 + m16;
        float bv = (MODE == 1) ? bias[gn] : 0.f;
#pragma unroll
        for (int ti = 0; ti < TI; ++ti) {
            int lr0 = wm + ti * 16 + q * 4;
            ushort4v h;
#pragma unroll
            for (int r = 0; r < 4; ++r) {
                float v = acc[ti][tj][r];
                if (MODE == 1) {
                    v += bv;
                    v = v / (1.f + __expf(-v));
                }
                u16 hv = f2bf(v);
                h[r] = hv;
                As[(lr0 + r) * 64 + tj * 16 + m16] = hv;
            }
            if (MODE == 1)
                *(ushort4v*)(Cb1 + (size_t)gn * 2048 + bm + lr0) = h;
        }
    }
    __syncthreads();
    {
        const int TPR = 256 / MROWS;       // threads per row (2 or 4)
        const int SPAN = 64 / TPR;         // cols per thread (32 or 16)
        int row = tid / TPR, part = tid % TPR;
        u16* gdst = Cb0 + (size_t)(bm + row) * 2048 + bn + part * SPAN;
        const u16* lsrc = As + row * 64 + part * SPAN;
#pragma unroll
        for (int i = 0; i < SPAN / 8; ++i)
            *(short8*)(gdst + i * 8) = *(const short8*)(lsrc + i * 8);
    }
}

// ---------------- G3: proj = u @ W_ssm, split-K=8 MFMA, interleaved atomics --------
#define APAD 40
__global__ __launch_bounds__(256) void g3_k(
    const u16* __restrict__ A,
    const u16* __restrict__ Bw,
    float* __restrict__ proj)
{
    __shared__ u16 As[128 * APAD];
    __shared__ u16 Bs[64 * APAD];
    const int tid = threadIdx.x;
    const int bn = blockIdx.x * 64;
    const int bm = blockIdx.y * 128;
    const int kb = blockIdx.z * 256;
    const int lane = tid & 63, wave = tid >> 6, wm = wave * 32;
    const int m16 = lane & 15, q = lane >> 4;
    floatx4 acc[2][4] = {};
    const int ar = tid >> 2, ac = (tid & 3) * 8;

    for (int kt = 0; kt < 8; ++kt) {
        const int k0 = kb + kt * 32;
#pragma unroll
        for (int p = 0; p < 2; ++p) {
            int r = ar + p * 64;
            *(short8*)(As + r * APAD + ac) =
                *(const short8*)(A + (size_t)(bm + r) * 2048 + k0 + ac);
        }
        *(short8*)(Bs + ar * APAD + ac) =
            *(const short8*)(Bw + (size_t)(bn + ar) * 2048 + k0 + ac);
        __syncthreads();

        short8 af[2], bfr[4];
#pragma unroll
        for (int ti = 0; ti < 2; ++ti)
            af[ti] = *(const short8*)(As + (wm + ti * 16 + m16) * APAD + q * 8);
#pragma unroll
        for (int tj = 0; tj < 4; ++tj)
            bfr[tj] = *(const short8*)(Bs + (tj * 16 + m16) * APAD + q * 8);
#pragma unroll
        for (int ti = 0; ti < 2; ++ti)
#pragma unroll
            for (int tj = 0; tj < 4; ++tj)
                acc[ti][tj] = __builtin_amdgcn_mfma_f32_16x16x32_bf16(
                    af[ti], bfr[tj], acc[ti][tj], 0, 0, 0);
        __syncthreads();
    }

#pragma unroll
    for (int tj = 0; tj < 4; ++tj) {
        int gn = bn + tj * 16 + m16;
        if (gn >= 96) continue;
        int col = (gn < 16) ? (2 * gn) : (gn < 32 ? 2 * (gn - 16) + 1 : 32 + gn);
#pragma unroll
        for (int ti = 0; ti < 2; ++ti)
#pragma unroll
            for (int r = 0; r < 4; ++r) {
                int gm = bm + wm + ti * 16 + q * 4 + r;
                atomicAdd(proj + (size_t)gm * 128 + col, acc[ti][tj][r]);
            }
    }
}

// ---------------- G4: deltaT = clip(softplus(dtraw @ W_dt + b_dt))^T (K=64) --------
__global__ __launch_bounds__(256) void g4_k(
    const u16* __restrict__ A,
    const u16* __restrict__ B,
    const float* __restrict__ bias,
    float* __restrict__ Cf)
{
    __shared__ u16 As[128 * APAD];
    __shared__ u16 Bs[64 * APAD];
    const int tid = threadIdx.x;
    const int bm = blockIdx.y * 128;
    const int bn = blockIdx.x * 64;
    const int lane = tid & 63, wave = tid >> 6, wm = wave * 32;
    const int m16 = lane & 15, q = lane >> 4;
    floatx4 acc[2][4] = {};
    const int ar = tid >> 2, ac = (tid & 3) * 8;

    for (int kt = 0; kt < 2; ++kt) {
        const int k0 = kt * 32;
#pragma unroll
        for (int p = 0; p < 2; ++p) {
            int r = ar + p * 64;
            *(short8*)(As + r * APAD + ac) =
                *(const short8*)(A + (size_t)(bm + r) * 64 + k0 + ac);
        }
        *(short8*)(Bs + ar * APAD + ac) =
            *(const short8*)(B + (size_t)(bn + ar) * 64 + k0 + ac);
        __syncthreads();
        short8 af[2], bfr[4];
#pragma unroll
        for (int ti = 0; ti < 2; ++ti)
            af[ti] = *(const short8*)(As + (wm + ti * 16 + m16) * APAD + q * 8);
#pragma unroll
        for (int tj = 0; tj < 4; ++tj)
            bfr[tj] = *(const short8*)(Bs + (tj * 16 + m16) * APAD + q * 8);
#pragma unroll
        for (int ti = 0; ti < 2; ++ti)
#pragma unroll
            for (int tj = 0; tj < 4; ++tj)
                acc[ti][tj] = __builtin_amdgcn_mfma_f32_16x16x32_bf16(
                    af[ti], bfr[tj], acc[ti][tj], 0, 0, 0);
        __syncthreads();
    }
#pragma unroll
    for (int tj = 0; tj < 4; ++tj) {
        int gn = bn + tj * 16 + m16;
        float bv = bias[gn];
#pragma unroll
        for (int ti = 0; ti < 2; ++ti) {
            int gm0 = bm + wm + ti * 16 + q * 4;
            float t[4];
#pragma unroll
            for (int r = 0; r < 4; ++r) {
                float v = acc[ti][tj][r] + bv;
                v = (v > 15.f) ? v : log1pf(__expf(v));
                t[r] = fminf(fmaxf(v, 0.001f), 0.1f);
            }
            *(float4*)(Cf + (size_t)gn * 2048 + gm0) =
                make_float4(t[0], t[1], t[2], t[3]);
        }
    }
}

// ---------------- scan7: lane=(c,n), DPP reduce, packed bc16, native exp2 ----------
__global__ __launch_bounds__(512) void scan7_k(
    const float* __restrict__ deltaT,  // [2048 h][2048 m]
    const u16* __restrict__ uT,        // [2048 h][2048 m] bf16
    const u16* __restrict__ bc16,      // [2048 m][32]: u32 n = B_n | C_n<<16
    const float* __restrict__ A_log,
    const float* __restrict__ Dvec,
    const u16* __restrict__ resT,      // [2048 h][2048 m] bf16
    u16* __restrict__ zT)              // [2048 h][2048 m] bf16
{
    __shared__ float lP[2][32][16], lS[2][32][16], lI[2][32][16];
    __shared__ float yrow[2048];
    const int h = blockIdx.x;
    const int tid = threadIdx.x;
    const int n = tid & 15;
    const int c = tid >> 4;        // 0..31
    const int l0 = c * 32;

    // ln2 folded in: exp(dt*Ahn) == exp2(dt*An2), native v_exp_f32
    const float An2 = -__expf(A_log[h * 16 + n]) * 1.442695041f;
    const float* drow = deltaT + (size_t)h * 2048;
    const u16*   urow = uT     + (size_t)h * 2048;

    float s0 = 0.f, s1 = 0.f, T0 = 0.f, T1 = 0.f;
    for (int j = 0; j < 32; ++j) {
        int l = l0 + j;
        float2 dtv = *(const float2*)(drow + 2 * l);
        u32 uv = *(const u32*)(urow + 2 * l);
        float uu0 = __uint_as_float(uv << 16);
        float uu1 = __uint_as_float(uv & 0xffff0000u);
        u32 w0 = *(const u32*)(bc16 + (size_t)(2 * l) * 32 + 2 * n);
        u32 w1 = *(const u32*)(bc16 + (size_t)(2 * l + 1) * 32 + 2 * n);
        float e0 = fexp2(dtv.x * An2);
        float e1 = fexp2(dtv.y * An2);
        s0 = fmaf(e0, s0, dtv.x * uu0 * __uint_as_float(w0 << 16));
        s1 = fmaf(e1, s1, dtv.y * uu1 * __uint_as_float(w1 << 16));
        T0 += dtv.x;
        T1 += dtv.y;
    }
    lP[0][c][n] = fexp2(T0 * An2); lS[0][c][n] = s0;
    lP[1][c][n] = fexp2(T1 * An2); lS[1][c][n] = s1;
    __syncthreads();
    if (tid < 32) {
        int bb = tid >> 4, nn = tid & 15;
        float X = 0.f;
#pragma unroll
        for (int cc = 0; cc < 32; ++cc) {
            lI[bb][cc][nn] = X;
            X = fmaf(lP[bb][cc][nn], X, lS[bb][cc][nn]);
        }
    }
    __syncthreads();

    s0 = lI[0][c][n];
    s1 = lI[1][c][n];
    const float Dh = Dvec[h];
    for (int j = 0; j < 32; ++j) {
        int l = l0 + j;
        float2 dtv = *(const float2*)(drow + 2 * l);
        u32 uv = *(const u32*)(urow + 2 * l);
        float uu0 = __uint_as_float(uv << 16);
        float uu1 = __uint_as_float(uv & 0xffff0000u);
        u32 w0 = *(const u32*)(bc16 + (size_t)(2 * l) * 32 + 2 * n);
        u32 w1 = *(const u32*)(bc16 + (size_t)(2 * l + 1) * 32 + 2 * n);
        float e0 = fexp2(dtv.x * An2);
        float e1 = fexp2(dtv.y * An2);
        s0 = fmaf(e0, s0, dtv.x * uu0 * __uint_as_float(w0 << 16));
        s1 = fmaf(e1, s1, dtv.y * uu1 * __uint_as_float(w1 << 16));
        float v0 = dpp_red16(__uint_as_float(w0 & 0xffff0000u) * s0);
        float v1 = dpp_red16(__uint_as_float(w1 & 0xffff0000u) * s1);
        if (n == 0) {
            yrow[2 * l]     = v0 + uu0 * Dh;
            yrow[2 * l + 1] = v1 + uu1 * Dh;
        }
    }
    __syncthreads();
    {
        int t0 = tid * 4;
        ushort4v rv = *(const ushort4v*)(resT + (size_t)h * 2048 + t0);
        u16 o[4];
#pragma unroll
        for (int i = 0; i < 4; ++i) {
            float r = bf2f(rv[i]);
            float y = yrow[t0 + i];
            o[i] = f2bf(y * (r / (1.f + __expf(-r))));
        }
        *(ulong1*)(zT + (size_t)h * 2048 + t0) = *(ulong1*)o;
    }
}

extern "C" void kernel_launch(void* const* d_in, const int* in_sizes, int n_in,
                              void* d_out, int out_size, void* d_ws, size_t ws_size,
                              hipStream_t stream)
{
    const float* x      = (const float*)d_in[0];
    const float* W_in   = (const float*)d_in[1];
    const float* W_conv = (const float*)d_in[2];
    const float* b_conv = (const float*)d_in[3];
    const float* A_log  = (const float*)d_in[4];
    const float* Dv     = (const float*)d_in[5];
    const float* W_ssm  = (const float*)d_in[6];
    const float* W_dt   = (const float*)d_in[7];
    const float* b_dt   = (const float*)d_in[8];
    const float* W_out  = (const float*)d_in[9];
    float* out = (float*)d_out;

    char* wsc = (char*)d_ws;
    u16*   xb     = (u16*)wsc;                 // ws+0 (..G1)
    float* projb  = (float*)wsc;               // ws+0 (G3..scan) — ALIASES xb!
    u16*   pb_dt  = (u16*)(wsc + (2u << 20));
    u16*   bc16   = (u16*)(wsc + (3u << 20));
    u16*   WT_in  = (u16*)(wsc + (4u << 20));
    u16*   u_mh   = (u16*)(wsc + (4u << 20));
    u16*   z_mh   = (u16*)(wsc + (4u << 20));
    u16*   xsbf   = (u16*)(wsc + (12u << 20));
    u16*   zT     = xsbf;
    u16*   resT   = (u16*)(wsc + (20u << 20));
    u16*   WT_cv  = (u16*)(wsc + (28u << 20));
    float* deltaT = (float*)(wsc + (28u << 20));
    u16*   uT     = (u16*)(wsc + (44u << 20));
    u16*   WT_out = (u16*)(wsc + (52u << 20));
    u16*   WT_ssm = (u16*)(wsc + (56u << 20));
    u16*   WT_dt  = (u16*)(wsc + (56u << 20) + (512u << 10));

    dim3 blk(256);

    // prep: 5 transposes + x convert, one launch
    prep_k<<<dim3(5728), blk, 0, stream>>>(
        W_conv, WT_cv, W_in, WT_in, W_out, WT_out, W_ssm, WT_ssm, W_dt, WT_dt,
        x, xb);

    // out memset is safe early: d_out aliases nothing in ws
    hipMemsetAsync(out, 0, 2048 * 1024 * sizeof(float), stream);

    // G1: xs[m][ch] | resT[h][m]  (last reader of xb)
    gls_k<0, 128><<<dim3(64, 16), blk, 0, stream>>>(
        xb, 1024, WT_in, 1024, nullptr, 0, xsbf, resT, nullptr, 16);

    // projb memset MUST be after G1: projb aliases xb (ws+0)
    hipMemsetAsync(projb, 0, 2048 * 128 * sizeof(float), stream);

    // C: conv -> u_mh + uT  (64x64 tiles, 1024 blocks = 4/CU)
    gls_k<1, 64><<<dim3(32, 32), blk, 0, stream>>>(
        xsbf, 2048, WT_cv, 4096, nullptr, 0, u_mh, uT, b_conv, 64);

    // G3: proj (split-K=8 atomics)
    g3_k<<<dim3(2, 16, 8), blk, 0, stream>>>(u_mh, WT_ssm, projb);

    cvtp_k<<<dim3(192), blk, 0, stream>>>(projb, pb_dt, bc16);

    g4_k<<<dim3(32, 16), blk, 0, stream>>>(pb_dt, WT_dt, b_dt, deltaT);

    scan7_k<<<dim3(2048), dim3(512), 0, stream>>>(
        deltaT, uT, bc16, A_log, Dv, resT, zT);

    tbf_k<<<dim3(32, 32), blk, 0, stream>>>(zT, z_mh);

    // G5: out = z_mh @ WT_out^T, split-K=2, fp32 atomic accumulate
    gls_k<3, 128><<<dim3(16, 16, 2), blk, 0, stream>>>(
        z_mh, 2048, WT_out, 2048, out, 1024, nullptr, nullptr, nullptr, 16);
}

// Round 13
// 317.824 us; speedup vs baseline: 1.0700x; 1.0700x over previous
//
#include <hip/hip_runtime.h>
#include <math.h>

// L=1024 B=2 F=1024 E=2 H=2048 N=16 R=64 K=4, M=2048 rows (m = l*2+b).
// Round-13: conv restructured as tap-strip kernel (conv2_k):
//   per 64-chan chunk, stage ONE 134-row A-strip (covers all 4 tap shifts,
//   17 KB) + 4 B tap-tiles (32 KB), 64 MFMA per barrier pair (was 16).
//   A staging bytes/issues cut 3.75x, barriers cut 4x. 128x64 tile, 512 blks.
// Scan keeps builtin exp2 (r12 win). G1/G5/g3/g4/prep unchanged from r12.

typedef unsigned short u16;
typedef unsigned int u32;
typedef __attribute__((ext_vector_type(8))) short short8;
typedef __attribute__((ext_vector_type(4))) float floatx4;
typedef __attribute__((ext_vector_type(4))) u16 ushort4v;

__device__ __forceinline__ u16 f2bf(float f) {
    u32 u = __float_as_uint(f);
    return (u16)((u + 0x7fffu + ((u >> 16) & 1u)) >> 16);
}
__device__ __forceinline__ float bf2f(u16 v) {
    return __uint_as_float((u32)v << 16);
}
__device__ __forceinline__ float fexp2(float x) {
    return __builtin_amdgcn_exp2f(x);   // bare v_exp_f32
}

// 16-lane sum reduction on the VALU pipe (DPP), no DS ops.
__device__ __forceinline__ float dpp_red16(float v) {
    v += __uint_as_float((u32)__builtin_amdgcn_update_dpp(
        0, (int)__float_as_uint(v), 0xB1, 0xF, 0xF, true));
    v += __uint_as_float((u32)__builtin_amdgcn_update_dpp(
        0, (int)__float_as_uint(v), 0x4E, 0xF, 0xF, true));
    v += __uint_as_float((u32)__builtin_amdgcn_update_dpp(
        0, (int)__float_as_uint(v), 0x141, 0xF, 0xF, true));
    v += __uint_as_float((u32)__builtin_amdgcn_update_dpp(
        0, (int)__float_as_uint(v), 0x128, 0xF, 0xF, true));
    return v;
}

// async global->LDS, 16 bytes per lane
__device__ __forceinline__ void gl_lds16(const u16* g, u16* l) {
    auto gp = reinterpret_cast<const __attribute__((address_space(1))) u32*>(
        reinterpret_cast<uintptr_t>(g));
    auto lp = reinterpret_cast<__attribute__((address_space(3))) u32*>(
        reinterpret_cast<uintptr_t>(l));
    __builtin_amdgcn_global_load_lds(gp, lp, 16, 0, 0);
}

// ---------------- device transpose body (fp32 -> bf16, S[R][C] -> D[C][R]) --------
__device__ __forceinline__ void trans_dev(const float* __restrict__ S,
                                          u16* __restrict__ D, int R, int C,
                                          int bx, int by)
{
    __shared__ u16 t[64][65];
    int br = bx * 64;
    int bc = by * 64;
    int c = threadIdx.x & 63;
    int r0 = threadIdx.x >> 6;
#pragma unroll
    for (int i = 0; i < 16; ++i) {
        int r = r0 + i * 4;
        float v = 0.f;
        if (br + r < R && bc + c < C) v = S[(size_t)(br + r) * C + bc + c];
        t[r][c] = f2bf(v);
    }
    __syncthreads();
    int cc0 = threadIdx.x >> 4;
    int rr0 = (threadIdx.x & 15) * 4;
#pragma unroll
    for (int i = 0; i < 4; ++i) {
        int cc = i * 16 + cc0;
        if (bc + cc < C) {
            ushort4v o;
#pragma unroll
            for (int k = 0; k < 4; ++k) o[k] = t[rr0 + k][cc];
            *(ushort4v*)(D + (size_t)(bc + cc) * R + br + rr0) = o;
        }
    }
}

// ---------------- prep: all transposes + x convert, one launch ----------------
__global__ __launch_bounds__(256) void prep_k(
    const float* __restrict__ Wc, u16* __restrict__ WTc,
    const float* __restrict__ Wi, u16* __restrict__ WTi,
    const float* __restrict__ Wo, u16* __restrict__ WTo,
    const float* __restrict__ Ws, u16* __restrict__ WTs,
    const float* __restrict__ Wd, u16* __restrict__ WTd,
    const float* __restrict__ x,  u16* __restrict__ xb)
{
    int b = blockIdx.x;
    if (b < 2048) { trans_dev(Wc, WTc, 4096, 2048, b & 63, b >> 6); return; }
    b -= 2048;
    if (b < 1024) { trans_dev(Wi, WTi, 1024, 4096, b & 15, b >> 4); return; }
    b -= 1024;
    if (b < 512)  { trans_dev(Wo, WTo, 2048, 1024, b & 31, b >> 5); return; }
    b -= 512;
    if (b < 64)   { trans_dev(Ws, WTs, 2048, 96,   b & 31, b >> 5); return; }
    b -= 64;
    if (b < 32)   { trans_dev(Wd, WTd, 64, 2048,   0,      b);      return; }
    b -= 32;
    {   // x fp32 -> bf16, 2048 blocks
        int i = (b * 256 + threadIdx.x) * 4;
        float4 v = *(const float4*)(x + i);
        u16 o[4] = {f2bf(v.x), f2bf(v.y), f2bf(v.z), f2bf(v.w)};
        *(ulong1*)(xb + i) = *(ulong1*)o;
    }
}

// ---------------- bf16 [2048][2048] transpose (zT -> z_mh) ----------------
__global__ __launch_bounds__(256) void tbf_k(const u16* __restrict__ S,
                                             u16* __restrict__ D)
{
    __shared__ u16 t[64][68];
    int br = blockIdx.x * 64;
    int bc = blockIdx.y * 64;
    int c = threadIdx.x & 63;
    int r0 = threadIdx.x >> 6;
#pragma unroll
    for (int i = 0; i < 16; ++i) {
        int r = r0 + i * 4;
        t[r][c] = S[(size_t)(br + r) * 2048 + bc + c];
    }
    __syncthreads();
#pragma unroll
    for (int i = 0; i < 16; ++i) {
        int r = r0 + i * 4;
        D[(size_t)(bc + r) * 2048 + br + c] = t[c][r];
    }
}

// ------- proj converts: blocks 0..127 -> dt cols 64..127 to pb_dt bf16 [2048][64]
//         blocks 128..191 -> BC cols 0..31 to bc16 bf16 [2048][32]
__global__ __launch_bounds__(256) void cvtp_k(const float* __restrict__ proj,
                                              u16* __restrict__ pb,
                                              u16* __restrict__ bc)
{
    if (blockIdx.x < 128) {
        int g = blockIdx.x * 256 + threadIdx.x;
        int m = g >> 4, i = (g & 15) * 4;
        float4 v = *(const float4*)(proj + (size_t)m * 128 + 64 + i);
        u16 o[4] = {f2bf(v.x), f2bf(v.y), f2bf(v.z), f2bf(v.w)};
        *(ulong1*)(pb + (size_t)m * 64 + i) = *(ulong1*)o;
    } else {
        int g = (blockIdx.x - 128) * 256 + threadIdx.x;
        int m = g >> 3, i = (g & 7) * 4;
        float4 v = *(const float4*)(proj + (size_t)m * 128 + i);
        u16 o[4] = {f2bf(v.x), f2bf(v.y), f2bf(v.z), f2bf(v.w)};
        *(ulong1*)(bc + (size_t)m * 32 + i) = *(ulong1*)o;
    }
}

// ================= m97-style GEMM: A[M][K] x B[N][K]^T, tile 128x64, BK=64 =========
// MODE 0: G1 split — bn<2048: xs[m][h] via LDS repack; else resT[h][m] direct
// MODE 3: split-K (gridDim.z), fp32 atomicAdd into zeroed Cf
template<int MODE>
__global__ __launch_bounds__(256) void gls_k(
    const u16* __restrict__ A, int lda,
    const u16* __restrict__ B, int ldb,
    float* __restrict__ Cf, int ldc,
    u16* __restrict__ Cb0, u16* __restrict__ Cb1,
    const float* __restrict__ bias, int nkt)
{
    __shared__ u16 As[128 * 64];
    __shared__ u16 Bs[64 * 64];
    const int tid = threadIdx.x;
    const int bm = blockIdx.y * 128;
    const int bn = blockIdx.x * 64;
    const int kofs = (MODE == 3) ? blockIdx.z * nkt * 64 : 0;
    const int lane = tid & 63, wave = tid >> 6, wm = wave * 32;
    const int m16 = lane & 15, q = lane >> 4;
    floatx4 acc[2][4] = {};

    const int rsub = lane >> 3;
    const int pch  = lane & 7;

    for (int kt = 0; kt < nkt; ++kt) {
        const int k0 = kofs + kt * 64;
#pragma unroll
        for (int i = 0; i < 4; ++i) {
            int r = i * 32 + wave * 8 + rsub;
            int c = pch ^ (r & 7);
            gl_lds16(A + (size_t)(bm + r) * lda + k0 + c * 8,
                     As + i * 2048 + wave * 512);
        }
#pragma unroll
        for (int i = 0; i < 2; ++i) {
            int r = i * 32 + wave * 8 + rsub;
            int c = pch ^ (r & 7);
            gl_lds16(B + (size_t)(bn + r) * ldb + k0 + c * 8,
                     Bs + i * 2048 + wave * 512);
        }
        __syncthreads();

#pragma unroll
        for (int ks = 0; ks < 2; ++ks) {
            short8 af[2], bfr[4];
#pragma unroll
            for (int ti = 0; ti < 2; ++ti) {
                int r = wm + ti * 16 + m16;
                int p = (ks * 4 + q) ^ (r & 7);
                af[ti] = *(const short8*)(As + r * 64 + p * 8);
            }
#pragma unroll
            for (int tj = 0; tj < 4; ++tj) {
                int r = tj * 16 + m16;
                int p = (ks * 4 + q) ^ (r & 7);
                bfr[tj] = *(const short8*)(Bs + r * 64 + p * 8);
            }
#pragma unroll
            for (int ti = 0; ti < 2; ++ti)
#pragma unroll
                for (int tj = 0; tj < 4; ++tj)
                    acc[ti][tj] = __builtin_amdgcn_mfma_f32_16x16x32_bf16(
                        af[ti], bfr[tj], acc[ti][tj], 0, 0, 0);
        }
        __syncthreads();
    }

    if (MODE == 3) {
#pragma unroll
        for (int tj = 0; tj < 4; ++tj) {
            int gn = bn + tj * 16 + m16;
#pragma unroll
            for (int ti = 0; ti < 2; ++ti) {
                int gm0 = bm + wm + ti * 16 + q * 4;
#pragma unroll
                for (int r = 0; r < 4; ++r)
                    atomicAdd(Cf + (size_t)(gm0 + r) * ldc + gn, acc[ti][tj][r]);
            }
        }
        return;
    }
    if (MODE == 0 && bn >= 2048) {
#pragma unroll
        for (int tj = 0; tj < 4; ++tj) {
            int gn = bn + tj * 16 + m16;
#pragma unroll
            for (int ti = 0; ti < 2; ++ti) {
                int gm0 = bm + wm + ti * 16 + q * 4;
                ushort4v h;
#pragma unroll
                for (int r = 0; r < 4; ++r) h[r] = f2bf(acc[ti][tj][r]);
                *(ushort4v*)(Cb1 + (size_t)(gn - 2048) * 2048 + gm0) = h;
            }
        }
        return;
    }
    // MODE 0 xs-half: repack [m][h] tile via LDS
#pragma unroll
    for (int tj = 0; tj < 4; ++tj) {
#pragma unroll
        for (int ti = 0; ti < 2; ++ti) {
            int lr0 = wm + ti * 16 + q * 4;
#pragma unroll
            for (int r = 0; r < 4; ++r)
                As[(lr0 + r) * 64 + tj * 16 + m16] = f2bf(acc[ti][tj][r]);
        }
    }
    __syncthreads();
    {
        int row = tid >> 1, half = tid & 1;
        u16* gdst = Cb0 + (size_t)(bm + row) * 2048 + bn + half * 32;
        const u16* lsrc = As + row * 64 + half * 32;
#pragma unroll
        for (int i = 0; i < 4; ++i)
            *(short8*)(gdst + i * 8) = *(const short8*)(lsrc + i * 8);
    }
}

// ================= conv2: tap-strip conv GEMM, tile 128x64 ========================
// One A-strip (134 rows, all 4 tap shifts) + 4 B tap-tiles per 64-chan chunk.
__global__ __launch_bounds__(256) void conv2_k(
    const u16* __restrict__ A,      // xsbf [2048][2048]
    const u16* __restrict__ B,      // WT_cv [2048][4096]
    const float* __restrict__ bias,
    u16* __restrict__ Cb0,          // u_mh [m][h]
    u16* __restrict__ Cb1)          // uT [h][m]
{
    __shared__ u16 Astrip[136 * 64];    // rows: global bm-6 .. bm+129
    __shared__ u16 Bs[4 * 64 * 64];     // 4 tap tiles
    const int tid = threadIdx.x;
    const int bm = blockIdx.y * 128;
    const int bn = blockIdx.x * 64;
    const int gofs = (bn >= 1024) ? 1024 : 0;
    const int lane = tid & 63, wave = tid >> 6, wm = wave * 32;
    const int m16 = lane & 15, q = lane >> 4;
    floatx4 acc[2][4] = {};
    const int rsub = lane >> 3;
    const int pch  = lane & 7;

    for (int ch = 0; ch < 16; ++ch) {
        const int ck = ch * 64;
        // A strip: 4 full issues (rows 0..127) + wave-0 issue (rows 128..135)
#pragma unroll
        for (int i = 0; i < 4; ++i) {
            int r = i * 32 + wave * 8 + rsub;
            int c = pch ^ (r & 7);
            int rg = bm + r - 6;
            if (rg < 0) rg = 0;              // clamp; zero-fixed below
            gl_lds16(A + (size_t)rg * 2048 + gofs + ck + c * 8,
                     Astrip + i * 2048 + wave * 512);
        }
        if (wave == 0) {
            int r = 128 + rsub;
            int c = pch ^ (r & 7);
            int rg = bm + r - 6;
            if (rg > 2047) rg = 2047;        // tail rows unused by fragments
            gl_lds16(A + (size_t)rg * 2048 + gofs + ck + c * 8,
                     Astrip + 4 * 2048);
        }
        // B: 4 tap tiles, 2 issues each
#pragma unroll
        for (int t = 0; t < 4; ++t)
#pragma unroll
            for (int i = 0; i < 2; ++i) {
                int r = i * 32 + wave * 8 + rsub;
                int c = pch ^ (r & 7);
                gl_lds16(B + (size_t)(bn + r) * 4096 + t * 1024 + ck + c * 8,
                         Bs + t * 4096 + i * 2048 + wave * 512);
            }
        if (bm == 0) {   // causal zero: strip rows 0..5 (global rows -6..-1)
            asm volatile("s_waitcnt vmcnt(0)" ::: "memory");
            if (tid < 48)
                *(short8*)(Astrip + (tid >> 3) * 64 + (tid & 7) * 8) = short8{};
        }
        __syncthreads();

#pragma unroll
        for (int t = 0; t < 4; ++t) {
#pragma unroll
            for (int ks = 0; ks < 2; ++ks) {
                short8 af[2], bfr[4];
#pragma unroll
                for (int ti = 0; ti < 2; ++ti) {
                    int sr = wm + ti * 16 + m16 + 2 * t;   // tap shift in-strip
                    int p = (ks * 4 + q) ^ (sr & 7);
                    af[ti] = *(const short8*)(Astrip + sr * 64 + p * 8);
                }
#pragma unroll
                for (int tj = 0; tj < 4; ++tj) {
                    int br = tj * 16 + m16;
                    int p = (ks * 4 + q) ^ (br & 7);
                    bfr[tj] = *(const short8*)(Bs + t * 4096 + br * 64 + p * 8);
                }
#pragma unroll
                for (int ti = 0; ti < 2; ++ti)
#pragma unroll
                    for (int tj = 0; tj < 4; ++tj)
                        acc[ti][tj] = __builtin_amdgcn_mfma_f32_16x16x32_bf16(
                            af[ti], bfr[tj], acc[ti][tj], 0, 0, 0);
            }
        }
        __syncthreads();
    }

    // epilogue: +bias, silu -> u_mh (LDS repack) + uT direct
#pragma unroll
    for (int tj = 0; tj < 4; ++tj) {
        int gn = bn + tj * 16 + m16;
        float bv = bias[gn];
#pragma unroll
        for (int ti = 0; ti < 2; ++ti) {
            int lr0 = wm + ti * 16 + q * 4;
            ushort4v h;
#pragma unroll
            for (int r = 0; r < 4; ++r) {
                float v = acc[ti][tj][r] + bv;
                v = v / (1.f + __expf(-v));
                u16 hv = f2bf(v);
                h[r] = hv;
                Astrip[(lr0 + r) * 64 + tj * 16 + m16] = hv;
            }
            *(ushort4v*)(Cb1 + (size_t)gn * 2048 + bm + lr0) = h;
        }
    }
    __syncthreads();
    {
        int row = tid >> 1, half = tid & 1;
        u16* gdst = Cb0 + (size_t)(bm + row) * 2048 + bn + half * 32;
        const u16* lsrc = Astrip + row * 64 + half * 32;
#pragma unroll
        for (int i = 0; i < 4; ++i)
            *(short8*)(gdst + i * 8) = *(const short8*)(lsrc + i * 8);
    }
}

// ---------------- G3: proj = u @ W_ssm, split-K=8 MFMA, interleaved atomics --------
#define APAD 40
__global__ __launch_bounds__(256) void g3_k(
    const u16* __restrict__ A,
    const u16* __restrict__ Bw,
    float* __restrict__ proj)
{
    __shared__ u16 As[128 * APAD];
    __shared__ u16 Bs[64 * APAD];
    const int tid = threadIdx.x;
    const int bn = blockIdx.x * 64;
    const int bm = blockIdx.y * 128;
    const int kb = blockIdx.z * 256;
    const int lane = tid & 63, wave = tid >> 6, wm = wave * 32;
    const int m16 = lane & 15, q = lane >> 4;
    floatx4 acc[2][4] = {};
    const int ar = tid >> 2, ac = (tid & 3) * 8;

    for (int kt = 0; kt < 8; ++kt) {
        const int k0 = kb + kt * 32;
#pragma unroll
        for (int p = 0; p < 2; ++p) {
            int r = ar + p * 64;
            *(short8*)(As + r * APAD + ac) =
                *(const short8*)(A + (size_t)(bm + r) * 2048 + k0 + ac);
        }
        *(short8*)(Bs + ar * APAD + ac) =
            *(const short8*)(Bw + (size_t)(bn + ar) * 2048 + k0 + ac);
        __syncthreads();

        short8 af[2], bfr[4];
#pragma unroll
        for (int ti = 0; ti < 2; ++ti)
            af[ti] = *(const short8*)(As + (wm + ti * 16 + m16) * APAD + q * 8);
#pragma unroll
        for (int tj = 0; tj < 4; ++tj)
            bfr[tj] = *(const short8*)(Bs + (tj * 16 + m16) * APAD + q * 8);
#pragma unroll
        for (int ti = 0; ti < 2; ++ti)
#pragma unroll
            for (int tj = 0; tj < 4; ++tj)
                acc[ti][tj] = __builtin_amdgcn_mfma_f32_16x16x32_bf16(
                    af[ti], bfr[tj], acc[ti][tj], 0, 0, 0);
        __syncthreads();
    }

#pragma unroll
    for (int tj = 0; tj < 4; ++tj) {
        int gn = bn + tj * 16 + m16;
        if (gn >= 96) continue;
        int col = (gn < 16) ? (2 * gn) : (gn < 32 ? 2 * (gn - 16) + 1 : 32 + gn);
#pragma unroll
        for (int ti = 0; ti < 2; ++ti)
#pragma unroll
            for (int r = 0; r < 4; ++r) {
                int gm = bm + wm + ti * 16 + q * 4 + r;
                atomicAdd(proj + (size_t)gm * 128 + col, acc[ti][tj][r]);
            }
    }
}

// ---------------- G4: deltaT = clip(softplus(dtraw @ W_dt + b_dt))^T (K=64) --------
__global__ __launch_bounds__(256) void g4_k(
    const u16* __restrict__ A,
    const u16* __restrict__ B,
    const float* __restrict__ bias,
    float* __restrict__ Cf)
{
    __shared__ u16 As[128 * APAD];
    __shared__ u16 Bs[64 * APAD];
    const int tid = threadIdx.x;
    const int bm = blockIdx.y * 128;
    const int bn = blockIdx.x * 64;
    const int lane = tid & 63, wave = tid >> 6, wm = wave * 32;
    const int m16 = lane & 15, q = lane >> 4;
    floatx4 acc[2][4] = {};
    const int ar = tid >> 2, ac = (tid & 3) * 8;

    for (int kt = 0; kt < 2; ++kt) {
        const int k0 = kt * 32;
#pragma unroll
        for (int p = 0; p < 2; ++p) {
            int r = ar + p * 64;
            *(short8*)(As + r * APAD + ac) =
                *(const short8*)(A + (size_t)(bm + r) * 64 + k0 + ac);
        }
        *(short8*)(Bs + ar * APAD + ac) =
            *(const short8*)(B + (size_t)(bn + ar) * 64 + k0 + ac);
        __syncthreads();
        short8 af[2], bfr[4];
#pragma unroll
        for (int ti = 0; ti < 2; ++ti)
            af[ti] = *(const short8*)(As + (wm + ti * 16 + m16) * APAD + q * 8);
#pragma unroll
        for (int tj = 0; tj < 4; ++tj)
            bfr[tj] = *(const short8*)(Bs + (tj * 16 + m16) * APAD + q * 8);
#pragma unroll
        for (int ti = 0; ti < 2; ++ti)
#pragma unroll
            for (int tj = 0; tj < 4; ++tj)
                acc[ti][tj] = __builtin_amdgcn_mfma_f32_16x16x32_bf16(
                    af[ti], bfr[tj], acc[ti][tj], 0, 0, 0);
        __syncthreads();
    }
#pragma unroll
    for (int tj = 0; tj < 4; ++tj) {
        int gn = bn + tj * 16 + m16;
        float bv = bias[gn];
#pragma unroll
        for (int ti = 0; ti < 2; ++ti) {
            int gm0 = bm + wm + ti * 16 + q * 4;
            float t[4];
#pragma unroll
            for (int r = 0; r < 4; ++r) {
                float v = acc[ti][tj][r] + bv;
                v = (v > 15.f) ? v : log1pf(__expf(v));
                t[r] = fminf(fmaxf(v, 0.001f), 0.1f);
            }
            *(float4*)(Cf + (size_t)gn * 2048 + gm0) =
                make_float4(t[0], t[1], t[2], t[3]);
        }
    }
}

// ---------------- scan7: lane=(c,n), DPP reduce, packed bc16, native exp2 ----------
__global__ __launch_bounds__(512) void scan7_k(
    const float* __restrict__ deltaT,  // [2048 h][2048 m]
    const u16* __restrict__ uT,        // [2048 h][2048 m] bf16
    const u16* __restrict__ bc16,      // [2048 m][32]: u32 n = B_n | C_n<<16
    const float* __restrict__ A_log,
    const float* __restrict__ Dvec,
    const u16* __restrict__ resT,      // [2048 h][2048 m] bf16
    u16* __restrict__ zT)              // [2048 h][2048 m] bf16
{
    __shared__ float lP[2][32][16], lS[2][32][16], lI[2][32][16];
    __shared__ float yrow[2048];
    const int h = blockIdx.x;
    const int tid = threadIdx.x;
    const int n = tid & 15;
    const int c = tid >> 4;        // 0..31
    const int l0 = c * 32;

    const float An2 = -__expf(A_log[h * 16 + n]) * 1.442695041f;
    const float* drow = deltaT + (size_t)h * 2048;
    const u16*   urow = uT     + (size_t)h * 2048;

    float s0 = 0.f, s1 = 0.f, T0 = 0.f, T1 = 0.f;
    for (int j = 0; j < 32; ++j) {
        int l = l0 + j;
        float2 dtv = *(const float2*)(drow + 2 * l);
        u32 uv = *(const u32*)(urow + 2 * l);
        float uu0 = __uint_as_float(uv << 16);
        float uu1 = __uint_as_float(uv & 0xffff0000u);
        u32 w0 = *(const u32*)(bc16 + (size_t)(2 * l) * 32 + 2 * n);
        u32 w1 = *(const u32*)(bc16 + (size_t)(2 * l + 1) * 32 + 2 * n);
        float e0 = fexp2(dtv.x * An2);
        float e1 = fexp2(dtv.y * An2);
        s0 = fmaf(e0, s0, dtv.x * uu0 * __uint_as_float(w0 << 16));
        s1 = fmaf(e1, s1, dtv.y * uu1 * __uint_as_float(w1 << 16));
        T0 += dtv.x;
        T1 += dtv.y;
    }
    lP[0][c][n] = fexp2(T0 * An2); lS[0][c][n] = s0;
    lP[1][c][n] = fexp2(T1 * An2); lS[1][c][n] = s1;
    __syncthreads();
    if (tid < 32) {
        int bb = tid >> 4, nn = tid & 15;
        float X = 0.f;
#pragma unroll
        for (int cc = 0; cc < 32; ++cc) {
            lI[bb][cc][nn] = X;
            X = fmaf(lP[bb][cc][nn], X, lS[bb][cc][nn]);
        }
    }
    __syncthreads();

    s0 = lI[0][c][n];
    s1 = lI[1][c][n];
    const float Dh = Dvec[h];
    for (int j = 0; j < 32; ++j) {
        int l = l0 + j;
        float2 dtv = *(const float2*)(drow + 2 * l);
        u32 uv = *(const u32*)(urow + 2 * l);
        float uu0 = __uint_as_float(uv << 16);
        float uu1 = __uint_as_float(uv & 0xffff0000u);
        u32 w0 = *(const u32*)(bc16 + (size_t)(2 * l) * 32 + 2 * n);
        u32 w1 = *(const u32*)(bc16 + (size_t)(2 * l + 1) * 32 + 2 * n);
        float e0 = fexp2(dtv.x * An2);
        float e1 = fexp2(dtv.y * An2);
        s0 = fmaf(e0, s0, dtv.x * uu0 * __uint_as_float(w0 << 16));
        s1 = fmaf(e1, s1, dtv.y * uu1 * __uint_as_float(w1 << 16));
        float v0 = dpp_red16(__uint_as_float(w0 & 0xffff0000u) * s0);
        float v1 = dpp_red16(__uint_as_float(w1 & 0xffff0000u) * s1);
        if (n == 0) {
            yrow[2 * l]     = v0 + uu0 * Dh;
            yrow[2 * l + 1] = v1 + uu1 * Dh;
        }
    }
    __syncthreads();
    {
        int t0 = tid * 4;
        ushort4v rv = *(const ushort4v*)(resT + (size_t)h * 2048 + t0);
        u16 o[4];
#pragma unroll
        for (int i = 0; i < 4; ++i) {
            float r = bf2f(rv[i]);
            float y = yrow[t0 + i];
            o[i] = f2bf(y * (r / (1.f + __expf(-r))));
        }
        *(ulong1*)(zT + (size_t)h * 2048 + t0) = *(ulong1*)o;
    }
}

extern "C" void kernel_launch(void* const* d_in, const int* in_sizes, int n_in,
                              void* d_out, int out_size, void* d_ws, size_t ws_size,
                              hipStream_t stream)
{
    const float* x      = (const float*)d_in[0];
    const float* W_in   = (const float*)d_in[1];
    const float* W_conv = (const float*)d_in[2];
    const float* b_conv = (const float*)d_in[3];
    const float* A_log  = (const float*)d_in[4];
    const float* Dv     = (const float*)d_in[5];
    const float* W_ssm  = (const float*)d_in[6];
    const float* W_dt   = (const float*)d_in[7];
    const float* b_dt   = (const float*)d_in[8];
    const float* W_out  = (const float*)d_in[9];
    float* out = (float*)d_out;

    char* wsc = (char*)d_ws;
    u16*   xb     = (u16*)wsc;                 // ws+0 (..G1)
    float* projb  = (float*)wsc;               // ws+0 (G3..scan) — ALIASES xb!
    u16*   pb_dt  = (u16*)(wsc + (2u << 20));
    u16*   bc16   = (u16*)(wsc + (3u << 20));
    u16*   WT_in  = (u16*)(wsc + (4u << 20));
    u16*   u_mh   = (u16*)(wsc + (4u << 20));
    u16*   z_mh   = (u16*)(wsc + (4u << 20));
    u16*   xsbf   = (u16*)(wsc + (12u << 20));
    u16*   zT     = xsbf;
    u16*   resT   = (u16*)(wsc + (20u << 20));
    u16*   WT_cv  = (u16*)(wsc + (28u << 20));
    float* deltaT = (float*)(wsc + (28u << 20));
    u16*   uT     = (u16*)(wsc + (44u << 20));
    u16*   WT_out = (u16*)(wsc + (52u << 20));
    u16*   WT_ssm = (u16*)(wsc + (56u << 20));
    u16*   WT_dt  = (u16*)(wsc + (56u << 20) + (512u << 10));

    dim3 blk(256);

    // prep: 5 transposes + x convert, one launch
    prep_k<<<dim3(5728), blk, 0, stream>>>(
        W_conv, WT_cv, W_in, WT_in, W_out, WT_out, W_ssm, WT_ssm, W_dt, WT_dt,
        x, xb);

    // out memset is safe early: d_out aliases nothing in ws
    hipMemsetAsync(out, 0, 2048 * 1024 * sizeof(float), stream);

    // G1: xs[m][ch] | resT[h][m]  (last reader of xb)
    gls_k<0><<<dim3(64, 16), blk, 0, stream>>>(
        xb, 1024, WT_in, 1024, nullptr, 0, xsbf, resT, nullptr, 16);

    // projb memset MUST be after G1: projb aliases xb (ws+0)
    hipMemsetAsync(projb, 0, 2048 * 128 * sizeof(float), stream);

    // C: tap-strip conv -> u_mh + uT
    conv2_k<<<dim3(32, 16), blk, 0, stream>>>(xsbf, WT_cv, b_conv, u_mh, uT);

    // G3: proj (split-K=8 atomics)
    g3_k<<<dim3(2, 16, 8), blk, 0, stream>>>(u_mh, WT_ssm, projb);

    cvtp_k<<<dim3(192), blk, 0, stream>>>(projb, pb_dt, bc16);

    g4_k<<<dim3(32, 16), blk, 0, stream>>>(pb_dt, WT_dt, b_dt, deltaT);

    scan7_k<<<dim3(2048), dim3(512), 0, stream>>>(
        deltaT, uT, bc16, A_log, Dv, resT, zT);

    tbf_k<<<dim3(32, 32), blk, 0, stream>>>(zT, z_mh);

    // G5: out = z_mh @ WT_out^T, split-K=2, fp32 atomic accumulate
    gls_k<3><<<dim3(16, 16, 2), blk, 0, stream>>>(
        z_mh, 2048, WT_out, 2048, out, 1024, nullptr, nullptr, nullptr, 16);
}